// Round 26
// baseline (126.216 us; speedup 1.0000x reference)
//
#include <hip/hip_runtime.h>
#include <hip/hip_bf16.h>
#include <stdint.h>
#include <stddef.h>

#define DIM 1024
#define SEQ 2048
#define KF 24

using f32x4    = __attribute__((ext_vector_type(4))) float;
using bf16x8   = __attribute__((ext_vector_type(8))) short;
using uint32x4 = __attribute__((ext_vector_type(4))) unsigned int;

__device__ __forceinline__ unsigned short f2bf(float f){
  union { float f; unsigned int i; } v; v.f = f;
  unsigned int r = v.i + 0x7FFFu + ((v.i >> 16) & 1u);  // RNE
  return (unsigned short)(r >> 16);
}
// D = a.bf16[0]*b.bf16[0] + a.bf16[1]*b.bf16[1] + c   (V_DOT2_F32_BF16, VOP3P)
__device__ __forceinline__ float dot2bf(unsigned int a, unsigned int b, float c){
  float d;
  asm("v_dot2_f32_bf16 %0, %1, %2, %3" : "=v"(d) : "v"(a), "v"(b), "v"(c));
  return d;
}
// D = low32({a,b} >> 16): lo16 = b.hi, hi16 = a.lo
__device__ __forceinline__ unsigned abit16(unsigned a, unsigned b){
  unsigned d;
  asm("v_alignbit_b32 %0, %1, %2, 16" : "=v"(d) : "v"(a), "v"(b));
  return d;
}
__device__ __forceinline__ unsigned vext(const uint32x4 v, int i){
  return i == 0 ? v.x : i == 1 ? v.y : i == 2 ? v.z : v.w;
}
__device__ __forceinline__ void gload_lds16(const void* g, void* l){
  __builtin_amdgcn_global_load_lds(
      (const __attribute__((address_space(1))) unsigned int*)g,
      (__attribute__((address_space(3))) unsigned int*)l, 16, 0, 0);
}

// ---------------- prep: x fp32 -> bf16 ----------------
__global__ void k_cvt_x(const float* __restrict__ x, unsigned short* __restrict__ xb){
  int i = blockIdx.x * 256 + threadIdx.x;            // each thread 4 elems
  const float4* x4 = (const float4*)x;
  float4 v = x4[i];
  ushort4 o;
  o.x = f2bf(v.x); o.y = f2bf(v.y); o.z = f2bf(v.z); o.w = f2bf(v.w);
  *(ushort4*)(xb + (size_t)i * 4) = o;
}

// ---------------- prep: M_inputs transpose -> bf16 (B^T, [d][e]) ----------------
__global__ void k_tr_M(const float* __restrict__ Mi, unsigned short* __restrict__ MbT){
  __shared__ float tile[32][33];
  int e0 = blockIdx.y * 32, d0 = blockIdx.x * 32;
  int tx = threadIdx.x, ty = threadIdx.y;            // block (32,8)
  #pragma unroll
  for (int r = 0; r < 32; r += 8)
    tile[ty + r][tx] = Mi[(size_t)(e0 + ty + r) * DIM + d0 + tx];
  __syncthreads();
  #pragma unroll
  for (int r = 0; r < 32; r += 8)
    MbT[(size_t)(d0 + ty + r) * DIM + e0 + tx] = f2bf(tile[tx][ty + r]);
}

// ---------------- prep: pe packed pairs, SWAPPED, chunk-interleaved [k][d][8] -------
// pepk2[k][d][i] = u32{ lo = pe_odd, hi = pe_even } for tap pair r2 = 8k+i.
// Swapped so dot2 against the alignbit-built y-pair (lo=y_{j-1}, hi=y_j)
// gives pe_even*y_j + pe_odd*y_{j-1}.
__global__ void k_pe(const float* __restrict__ filters, const float* __restrict__ Mf,
                     unsigned int* __restrict__ pepk2){
  int r2 = blockIdx.x * 256 + threadIdx.x;           // 0..511 (grid.x = 2)
  int d  = blockIdx.y;                               // 0..1023
  float a0 = 0.f, a1 = 0.f;
  #pragma unroll
  for (int k = 0; k < KF; ++k){
    float mf = Mf[(size_t)k * DIM + d];              // uniform per block
    a0 += filters[(size_t)(4 * r2)     * KF + k] * mf;
    a1 += filters[(size_t)(4 * r2 + 2) * KF + k] * mf;
  }
  unsigned int lo = f2bf(2.f * a1), hi = f2bf(2.f * a0);   // SWAPPED
  pepk2[(size_t)(r2 >> 3) * 8192 + (size_t)d * 8 + (r2 & 7)] = lo | (hi << 16);
}

// ---------------- GEMM: x_proj = x @ M_inputs, epilogue writes PLAIN y8 ------------
// y8 u16 element (b,p,j,d) at index (b*2+p)*1048576 + (j>>3)*8192 + d*8 + (j&7).
#define BM 128
#define BN 128
#define BKK 64
__global__ void k_gemm(const unsigned short* __restrict__ A,
                       const unsigned short* __restrict__ Bt,
                       unsigned short* __restrict__ Y8){
  __shared__ unsigned short As[BM * BKK];   // 16 KB, XOR-swizzled (unit16B ^= row&7)
  __shared__ unsigned short Bs[BN * BKK];   // 16 KB
  int tid  = threadIdx.x;
  int lane = tid & 63, wave = tid >> 6;
  int wm = wave >> 1, wn = wave & 1;
  int trow0 = blockIdx.x * BM;
  int ncol0 = blockIdx.y * BN;

  f32x4 acc[4][4] = {};

  for (int kt = 0; kt < 1024 / BKK; ++kt){
    __syncthreads();
    #pragma unroll
    for (int g = 0; g < 4; ++g){
      int c  = wave * 4 + g;              // chunk 0..15, 1KB each
      int mr = c * 8 + (lane >> 3);       // tile row this lane stages
      int u  = lane & 7;                  // physical 16B unit within row
      int su = u ^ (mr & 7);              // source (logical) unit
      const unsigned short* srcA = A + (size_t)(trow0 + mr) * 1024 + kt * BKK + su * 8;
      gload_lds16(srcA, (char*)As + c * 1024);
      const unsigned short* srcB = Bt + (size_t)(ncol0 + mr) * 1024 + kt * BKK + su * 8;
      gload_lds16(srcB, (char*)Bs + c * 1024);
    }
    __syncthreads();

    bf16x8 af[4][2], bfr[4][2];
    #pragma unroll
    for (int mi = 0; mi < 4; ++mi){
      int row = wm * 64 + mi * 16 + (lane & 15);
      #pragma unroll
      for (int ks = 0; ks < 2; ++ks){
        int u = ((lane >> 4) + 4 * ks) ^ (row & 7);
        af[mi][ks] = *(const bf16x8*)((const char*)As + row * 128 + u * 16);
      }
    }
    #pragma unroll
    for (int ni = 0; ni < 4; ++ni){
      int row = wn * 64 + ni * 16 + (lane & 15);
      #pragma unroll
      for (int ks = 0; ks < 2; ++ks){
        int u = ((lane >> 4) + 4 * ks) ^ (row & 7);
        bfr[ni][ks] = *(const bf16x8*)((const char*)Bs + row * 128 + u * 16);
      }
    }
    #pragma unroll
    for (int mi = 0; mi < 4; ++mi)
      #pragma unroll
      for (int ni = 0; ni < 4; ++ni)
        #pragma unroll
        for (int ks = 0; ks < 2; ++ks)
          acc[mi][ni] = __builtin_amdgcn_mfma_f32_16x16x32_bf16(
              af[mi][ks], bfr[ni][ks], acc[mi][ni], 0, 0, 0);
  }

  #pragma unroll
  for (int mi = 0; mi < 4; ++mi)
    #pragma unroll
    for (int ni = 0; ni < 4; ++ni){
      int col = ncol0 + wn * 64 + ni * 16 + (lane & 15);
      #pragma unroll
      for (int reg = 0; reg < 4; ++reg){
        int row = trow0 + wm * 64 + mi * 16 + (lane >> 4) * 4 + reg;
        unsigned short y = f2bf(acc[mi][ni][reg]);
        int t = row & 2047, bq = row >> 11;
        int p = t & 1, j = t >> 1;
        size_t e = ((size_t)(bq * 2 + p)) * 1048576 +
                   (size_t)(j >> 3) * 8192 + (size_t)col * 8 + (j & 7);
        Y8[e] = y;
      }
    }
}

// ---------------- depthwise causal conv: R25 base + early load issue + split waits --
// out[m0+m] = sum_{r<=m0+m} pe[r]*y[m0+m-r], m in [0,32), one tile per block.
// Changes vs passing R25 (91us, VALUBusy 66%): (1) the 4 loads for chunk c+1
// are issued at the TOP of BODY (r0/r1/npv are dead there) -> latency cover
// grows from ~820cy (phase_mid_new only) to ~1050cy (phase_old too);
// (2) split waits: vmcnt(2) before build_pairs (x loads only; pe still in
// flight), vmcnt(0) after (pe needed for next phase_old);
// (3) LDS throttle 53248 -> 3 blocks/CU = 3 waves/SIMD of mutual stall cover
// (was 2), backfill still active (1024 blocks > 768 slots).
#define GLD4(dst, vo, base) do{ unsigned _vo = (vo);                             \
  asm volatile("global_load_dwordx4 %0, %1, %2"                                  \
               : "=v"(dst) : "v"(_vo), "s"(base)); }while(0)

__device__ __forceinline__ void phase_old(const unsigned* PA, const uint32x4* pv,
                                          float* acc){
  #pragma unroll
  for (int q = 0; q < 8; ++q)
    #pragma unroll
    for (int m = 0; m < 32; ++m){
      int idx = m - 2 * q + 16;
      if (idx >= 2 && idx < 16)
        acc[m] = dot2bf(vext(pv[q >> 2], q & 3), PA[idx], acc[m]);
    }
}
__device__ __forceinline__ void phase_mid_new(const unsigned* PM, const unsigned* PN,
                                              const uint32x4* pv, float* acc){
  #pragma unroll
  for (int q = 0; q < 8; ++q)
    #pragma unroll
    for (int m = 0; m < 32; ++m){
      int idx = m - 2 * q + 16;
      if (idx >= 16){
        unsigned w = (idx < 32) ? PM[idx - 16] : PN[idx - 32];
        acc[m] = dot2bf(vext(pv[q >> 2], q & 3), w, acc[m]);
      }
    }
}
// P[2i] = (lo=y_{2i-1}, hi=y_{2i}) via alignbit; P[2i+1] = w_i = (y_{2i}, y_{2i+1})
__device__ __forceinline__ void build_pairs(unsigned* P, uint32x4 r0, uint32x4 r1,
                                            unsigned& carry){
  unsigned w0 = r0.x, w1 = r0.y, w2 = r0.z, w3 = r0.w;
  unsigned w4 = r1.x, w5 = r1.y, w6 = r1.z, w7 = r1.w;
  P[0]  = abit16(w0, carry); P[1]  = w0;
  P[2]  = abit16(w1, w0);    P[3]  = w1;
  P[4]  = abit16(w2, w1);    P[5]  = w2;
  P[6]  = abit16(w3, w2);    P[7]  = w3;
  P[8]  = abit16(w4, w3);    P[9]  = w4;
  P[10] = abit16(w5, w4);    P[11] = w5;
  P[12] = abit16(w6, w5);    P[13] = w6;
  P[14] = abit16(w7, w6);    P[15] = w7;
  carry = w7;
}

#define BODY(PA_, PM_, PN_, C) do{                                               \
  { unsigned _g = (unsigned)(2 * ((C) + 1)) & 127u;   /* dead prefetch wraps */  \
    GLD4(r0, voff + _g * 16384u, xb);                                            \
    GLD4(r1, voff + _g * 16384u + 16384u, xb);                                   \
    int _pr = (int)pbase - 32768 * ((C) + 1);                                    \
    unsigned _ps = (_pr < 0) ? 0u : (unsigned)_pr;    /* dead prefetch clamps */ \
    GLD4(npv[0], pvoff + _ps, pb);                                               \
    GLD4(npv[1], pvoff + _ps + 16u, pb); }                                       \
  __builtin_amdgcn_sched_barrier(0);                                             \
  phase_old(PA_, pv, acc);                                                       \
  phase_mid_new(PM_, PN_, pv, acc);                                              \
  asm volatile("s_waitcnt vmcnt(2)" ::: "memory");                               \
  __builtin_amdgcn_sched_barrier(0);                                             \
  build_pairs(PA_, r0, r1, carry);                                               \
  asm volatile("s_waitcnt vmcnt(0)" ::: "memory");                               \
  __builtin_amdgcn_sched_barrier(0);                                             \
  pv[0] = npv[0]; pv[1] = npv[1];                                                \
}while(0)

__global__ __launch_bounds__(256, 4)
void k_conv(const unsigned short* __restrict__ Y8,   // plain y8 (see k_gemm)
            const unsigned int* __restrict__ pepk2,  // [64][1024][8] pe pairs
            float* __restrict__ out){                // [4][2048][1024] f32
  int tid  = threadIdx.x;
  int bid  = blockIdx.x;                    // 0..1023
  int bp   = bid & 7;                       // XCD pin: stream -> one XCD
  int rest = bid >> 3;                      // 0..127
  int dblk = rest & 3;
  int mt   = 31 - (rest >> 2);              // LPT: longest tiles dispatch first
  int b = bp >> 1, p = bp & 1;
  int d = dblk * 256 + tid;                 // 0..1023

  const unsigned short* xb = Y8 + (size_t)bp * 1048576;  // uniform, loop-invariant
  const unsigned int*   pb = pepk2;                      // uniform, loop-invariant

  unsigned voff  = (unsigned)(d * 16);      // lane's 16B (8 y) within a j-group
  unsigned pvoff = (unsigned)(d * 32);      // lane's 32B pe record within a chunk

  unsigned P0[16], P1[16], P2[16];
  uint32x4 r0, r1, pv[2], npv[2];
  float acc[32];
  unsigned carry = 0u;

  unsigned pbase = (2u * (unsigned)mt + 1u) * 32768u;  // pe chunk-0 byte offset
  int nch = 2 * mt + 2;

  #pragma unroll
  for (int m = 0; m < 32; ++m) acc[m] = 0.f;
  #pragma unroll
  for (int t = 0; t < 16; ++t){ P0[t] = 0u; P1[t] = 0u; }  // groups -2, -1 (j<0)

  // prologue: group 0 raw + pe chunk 0
  GLD4(r0, voff, xb);
  GLD4(r1, voff + 16384u, xb);
  GLD4(pv[0], pvoff + pbase, pb);
  GLD4(pv[1], pvoff + pbase + 16u, pb);
  asm volatile("s_waitcnt vmcnt(0)" ::: "memory");
  __builtin_amdgcn_sched_barrier(0);
  build_pairs(P2, r0, r1, carry);           // group 0 (y_{-1} = carry 0)

  int c = 0;
  for (;;){
    BODY(P0, P1, P2, c); if (++c == nch) break;
    BODY(P1, P2, P0, c); if (++c == nch) break;
    BODY(P2, P0, P1, c); if (++c == nch) break;
  }

  float* oc = out + ((size_t)(b * SEQ + p) * 1024 + d) + (size_t)mt * 32 * 2048;
  #pragma unroll
  for (int m = 0; m < 32; ++m)
    __builtin_nontemporal_store(acc[m], oc + (size_t)m * 2048);
}

extern "C" void kernel_launch(void* const* d_in, const int* in_sizes, int n_in,
                              void* d_out, int out_size, void* d_ws, size_t ws_size,
                              hipStream_t stream){
  const float* x       = (const float*)d_in[0];
  const float* filters = (const float*)d_in[1];
  const float* Mi      = (const float*)d_in[2];
  const float* Mf      = (const float*)d_in[3];

  char* ws = (char*)d_ws;
  unsigned short* Xb    = (unsigned short*)(ws);                              // 16 MB
  unsigned short* Y8    = (unsigned short*)(ws + (size_t)16 * 1024 * 1024);   // 16 MB
  unsigned short* MbT   = (unsigned short*)(ws + (size_t)48 * 1024 * 1024);   //  2 MB
  unsigned int*   pepk2 = (unsigned int*)  (ws + (size_t)50 * 1024 * 1024);   //  2 MB
  float* out = (float*)d_out;

  hipLaunchKernelGGL(k_cvt_x, dim3(8192), dim3(256), 0, stream, x, Xb);
  hipLaunchKernelGGL(k_tr_M,  dim3(32, 32), dim3(32, 8), 0, stream, Mi, MbT);
  hipLaunchKernelGGL(k_pe,    dim3(2, 1024), dim3(256), 0, stream, filters, Mf, pepk2);
  hipLaunchKernelGGL(k_gemm,  dim3(64, 8), dim3(256), 0, stream, Xb, MbT, Y8);
  // 53248 B dynamic LDS per block: caps residency at 3 blocks/CU (160 KiB pool)
  // -> 768 resident slots serve 1024 LPT-ordered blocks with HW backfill.
  hipLaunchKernelGGL(k_conv,  dim3(1024), dim3(256), 53248, stream, Y8, pepk2, out);
}

// Round 27
// 120.164 us; speedup vs baseline: 1.0504x; 1.0504x over previous
//
#include <hip/hip_runtime.h>
#include <hip/hip_bf16.h>
#include <stdint.h>
#include <stddef.h>

#define DIM 1024
#define SEQ 2048
#define KF 24

using f32x4    = __attribute__((ext_vector_type(4))) float;
using bf16x8   = __attribute__((ext_vector_type(8))) short;
using uint32x4 = __attribute__((ext_vector_type(4))) unsigned int;

__device__ __forceinline__ unsigned short f2bf(float f){
  union { float f; unsigned int i; } v; v.f = f;
  unsigned int r = v.i + 0x7FFFu + ((v.i >> 16) & 1u);  // RNE
  return (unsigned short)(r >> 16);
}
// D = a.bf16[0]*b.bf16[0] + a.bf16[1]*b.bf16[1] + c   (V_DOT2_F32_BF16, VOP3P)
__device__ __forceinline__ float dot2bf(unsigned int a, unsigned int b, float c){
  float d;
  asm("v_dot2_f32_bf16 %0, %1, %2, %3" : "=v"(d) : "v"(a), "v"(b), "v"(c));
  return d;
}
// D = low32({a,b} >> 16): lo16 = b.hi, hi16 = a.lo
__device__ __forceinline__ unsigned abit16(unsigned a, unsigned b){
  unsigned d;
  asm("v_alignbit_b32 %0, %1, %2, 16" : "=v"(d) : "v"(a), "v"(b));
  return d;
}
__device__ __forceinline__ unsigned vext(const uint32x4 v, int i){
  return i == 0 ? v.x : i == 1 ? v.y : i == 2 ? v.z : v.w;
}
__device__ __forceinline__ void gload_lds16(const void* g, void* l){
  __builtin_amdgcn_global_load_lds(
      (const __attribute__((address_space(1))) unsigned int*)g,
      (__attribute__((address_space(3))) unsigned int*)l, 16, 0, 0);
}

// ---------------- prep: x fp32 -> bf16 ----------------
__global__ void k_cvt_x(const float* __restrict__ x, unsigned short* __restrict__ xb){
  int i = blockIdx.x * 256 + threadIdx.x;            // each thread 4 elems
  const float4* x4 = (const float4*)x;
  float4 v = x4[i];
  ushort4 o;
  o.x = f2bf(v.x); o.y = f2bf(v.y); o.z = f2bf(v.z); o.w = f2bf(v.w);
  *(ushort4*)(xb + (size_t)i * 4) = o;
}

// ---------------- prep: M_inputs transpose -> bf16 (B^T, [d][e]) ----------------
__global__ void k_tr_M(const float* __restrict__ Mi, unsigned short* __restrict__ MbT){
  __shared__ float tile[32][33];
  int e0 = blockIdx.y * 32, d0 = blockIdx.x * 32;
  int tx = threadIdx.x, ty = threadIdx.y;            // block (32,8)
  #pragma unroll
  for (int r = 0; r < 32; r += 8)
    tile[ty + r][tx] = Mi[(size_t)(e0 + ty + r) * DIM + d0 + tx];
  __syncthreads();
  #pragma unroll
  for (int r = 0; r < 32; r += 8)
    MbT[(size_t)(d0 + ty + r) * DIM + e0 + tx] = f2bf(tile[tx][ty + r]);
}

// ---------------- prep: pe packed pairs, SWAPPED, chunk-interleaved [k][d][8] -------
// pepk2[k][d][i] = u32{ lo = pe_odd, hi = pe_even } for tap pair r2 = 8k+i.
// Swapped so dot2 against the alignbit-built y-pair (lo=y_{j-1}, hi=y_j)
// gives pe_even*y_j + pe_odd*y_{j-1}.
__global__ void k_pe(const float* __restrict__ filters, const float* __restrict__ Mf,
                     unsigned int* __restrict__ pepk2){
  int r2 = blockIdx.x * 256 + threadIdx.x;           // 0..511 (grid.x = 2)
  int d  = blockIdx.y;                               // 0..1023
  float a0 = 0.f, a1 = 0.f;
  #pragma unroll
  for (int k = 0; k < KF; ++k){
    float mf = Mf[(size_t)k * DIM + d];              // uniform per block
    a0 += filters[(size_t)(4 * r2)     * KF + k] * mf;
    a1 += filters[(size_t)(4 * r2 + 2) * KF + k] * mf;
  }
  unsigned int lo = f2bf(2.f * a1), hi = f2bf(2.f * a0);   // SWAPPED
  pepk2[(size_t)(r2 >> 3) * 8192 + (size_t)d * 8 + (r2 & 7)] = lo | (hi << 16);
}

// ---------------- GEMM: x_proj = x @ M_inputs, epilogue writes PLAIN y8 ------------
// y8 u16 element (b,p,j,d) at index (b*2+p)*1048576 + (j>>3)*8192 + d*8 + (j&7).
#define BM 128
#define BN 128
#define BKK 64
__global__ void k_gemm(const unsigned short* __restrict__ A,
                       const unsigned short* __restrict__ Bt,
                       unsigned short* __restrict__ Y8){
  __shared__ unsigned short As[BM * BKK];   // 16 KB, XOR-swizzled (unit16B ^= row&7)
  __shared__ unsigned short Bs[BN * BKK];   // 16 KB
  int tid  = threadIdx.x;
  int lane = tid & 63, wave = tid >> 6;
  int wm = wave >> 1, wn = wave & 1;
  int trow0 = blockIdx.x * BM;
  int ncol0 = blockIdx.y * BN;

  f32x4 acc[4][4] = {};

  for (int kt = 0; kt < 1024 / BKK; ++kt){
    __syncthreads();
    #pragma unroll
    for (int g = 0; g < 4; ++g){
      int c  = wave * 4 + g;              // chunk 0..15, 1KB each
      int mr = c * 8 + (lane >> 3);       // tile row this lane stages
      int u  = lane & 7;                  // physical 16B unit within row
      int su = u ^ (mr & 7);              // source (logical) unit
      const unsigned short* srcA = A + (size_t)(trow0 + mr) * 1024 + kt * BKK + su * 8;
      gload_lds16(srcA, (char*)As + c * 1024);
      const unsigned short* srcB = Bt + (size_t)(ncol0 + mr) * 1024 + kt * BKK + su * 8;
      gload_lds16(srcB, (char*)Bs + c * 1024);
    }
    __syncthreads();

    bf16x8 af[4][2], bfr[4][2];
    #pragma unroll
    for (int mi = 0; mi < 4; ++mi){
      int row = wm * 64 + mi * 16 + (lane & 15);
      #pragma unroll
      for (int ks = 0; ks < 2; ++ks){
        int u = ((lane >> 4) + 4 * ks) ^ (row & 7);
        af[mi][ks] = *(const bf16x8*)((const char*)As + row * 128 + u * 16);
      }
    }
    #pragma unroll
    for (int ni = 0; ni < 4; ++ni){
      int row = wn * 64 + ni * 16 + (lane & 15);
      #pragma unroll
      for (int ks = 0; ks < 2; ++ks){
        int u = ((lane >> 4) + 4 * ks) ^ (row & 7);
        bfr[ni][ks] = *(const bf16x8*)((const char*)Bs + row * 128 + u * 16);
      }
    }
    #pragma unroll
    for (int mi = 0; mi < 4; ++mi)
      #pragma unroll
      for (int ni = 0; ni < 4; ++ni)
        #pragma unroll
        for (int ks = 0; ks < 2; ++ks)
          acc[mi][ni] = __builtin_amdgcn_mfma_f32_16x16x32_bf16(
              af[mi][ks], bfr[ni][ks], acc[mi][ni], 0, 0, 0);
  }

  #pragma unroll
  for (int mi = 0; mi < 4; ++mi)
    #pragma unroll
    for (int ni = 0; ni < 4; ++ni){
      int col = ncol0 + wn * 64 + ni * 16 + (lane & 15);
      #pragma unroll
      for (int reg = 0; reg < 4; ++reg){
        int row = trow0 + wm * 64 + mi * 16 + (lane >> 4) * 4 + reg;
        unsigned short y = f2bf(acc[mi][ni][reg]);
        int t = row & 2047, bq = row >> 11;
        int p = t & 1, j = t >> 1;
        size_t e = ((size_t)(bq * 2 + p)) * 1048576 +
                   (size_t)(j >> 3) * 8192 + (size_t)col * 8 + (j & 7);
        Y8[e] = y;
      }
    }
}

// ---------------- depthwise causal conv: plain-y8, global_load, v-only offsets -----
// out[m0+m] = sum_{r<=m0+m} pe[r]*y[m0+m-r], m in [0,32), one tile per block.
// Pair P'(j) = (lo=y_{j-1}, hi=y_j); dot2 with swapped pe == R18/R22 math.
// Per chunk c: phase_old (56 dot2, oldest pair slot) -> issue 2 x dwordx4
// (group c+1, 8KB) + 2 pe dwordx4 -> phase_mid_new (200 dot2) ->
// vmcnt(0)+sched_barrier (rule 18) -> build 16 pairs into the vacated slot
// (8 alignbit; odd pairs are raw words).  global_load with loop-invariant "s"
// base + VGPR offset (no loop-carried "s" operand -> compile-stable).  No
// consumed load is ever OOB (j<0 padding = zeroed P0/P1; final prefetches
// dead, clamped in-bounds).  This exact kernel measured 91us conv / 120.2us
// total (session best); R26's scheduling variants regressed -> reverted.
#define GLD4(dst, vo, base) do{ unsigned _vo = (vo);                             \
  asm volatile("global_load_dwordx4 %0, %1, %2"                                  \
               : "=v"(dst) : "v"(_vo), "s"(base)); }while(0)

__device__ __forceinline__ void phase_old(const unsigned* PA, const uint32x4* pv,
                                          float* acc){
  #pragma unroll
  for (int q = 0; q < 8; ++q)
    #pragma unroll
    for (int m = 0; m < 32; ++m){
      int idx = m - 2 * q + 16;
      if (idx >= 2 && idx < 16)
        acc[m] = dot2bf(vext(pv[q >> 2], q & 3), PA[idx], acc[m]);
    }
}
__device__ __forceinline__ void phase_mid_new(const unsigned* PM, const unsigned* PN,
                                              const uint32x4* pv, float* acc){
  #pragma unroll
  for (int q = 0; q < 8; ++q)
    #pragma unroll
    for (int m = 0; m < 32; ++m){
      int idx = m - 2 * q + 16;
      if (idx >= 16){
        unsigned w = (idx < 32) ? PM[idx - 16] : PN[idx - 32];
        acc[m] = dot2bf(vext(pv[q >> 2], q & 3), w, acc[m]);
      }
    }
}
// P[2i] = (lo=y_{2i-1}, hi=y_{2i}) via alignbit; P[2i+1] = w_i = (y_{2i}, y_{2i+1})
__device__ __forceinline__ void build_pairs(unsigned* P, uint32x4 r0, uint32x4 r1,
                                            unsigned& carry){
  unsigned w0 = r0.x, w1 = r0.y, w2 = r0.z, w3 = r0.w;
  unsigned w4 = r1.x, w5 = r1.y, w6 = r1.z, w7 = r1.w;
  P[0]  = abit16(w0, carry); P[1]  = w0;
  P[2]  = abit16(w1, w0);    P[3]  = w1;
  P[4]  = abit16(w2, w1);    P[5]  = w2;
  P[6]  = abit16(w3, w2);    P[7]  = w3;
  P[8]  = abit16(w4, w3);    P[9]  = w4;
  P[10] = abit16(w5, w4);    P[11] = w5;
  P[12] = abit16(w6, w5);    P[13] = w6;
  P[14] = abit16(w7, w6);    P[15] = w7;
  carry = w7;
}

#define BODY(PA_, PM_, PN_, C) do{                                               \
  phase_old(PA_, pv, acc);                                                       \
  __builtin_amdgcn_sched_barrier(0);                                             \
  { unsigned _g = (unsigned)(2 * ((C) + 1)) & 127u;   /* dead prefetch wraps */  \
    GLD4(r0, voff + _g * 16384u, xb);                                            \
    GLD4(r1, voff + _g * 16384u + 16384u, xb);                                   \
    int _pr = (int)pbase - 32768 * ((C) + 1);                                    \
    unsigned _ps = (_pr < 0) ? 0u : (unsigned)_pr;    /* dead prefetch clamps */ \
    GLD4(npv[0], pvoff + _ps, pb);                                               \
    GLD4(npv[1], pvoff + _ps + 16u, pb); }                                       \
  __builtin_amdgcn_sched_barrier(0);                                             \
  phase_mid_new(PM_, PN_, pv, acc);                                              \
  asm volatile("s_waitcnt vmcnt(0)" ::: "memory");                               \
  __builtin_amdgcn_sched_barrier(0);                                             \
  build_pairs(PA_, r0, r1, carry);                                               \
  pv[0] = npv[0]; pv[1] = npv[1];                                                \
}while(0)

__global__ __launch_bounds__(256, 4)
void k_conv(const unsigned short* __restrict__ Y8,   // plain y8 (see k_gemm)
            const unsigned int* __restrict__ pepk2,  // [64][1024][8] pe pairs
            float* __restrict__ out){                // [4][2048][1024] f32
  int tid  = threadIdx.x;
  int bid  = blockIdx.x;                    // 0..1023
  int bp   = bid & 7;                       // XCD pin: stream -> one XCD
  int rest = bid >> 3;                      // 0..127
  int dblk = rest & 3;
  int mt   = 31 - (rest >> 2);              // LPT: longest tiles dispatch first
  int b = bp >> 1, p = bp & 1;
  int d = dblk * 256 + tid;                 // 0..1023

  const unsigned short* xb = Y8 + (size_t)bp * 1048576;  // uniform, loop-invariant
  const unsigned int*   pb = pepk2;                      // uniform, loop-invariant

  unsigned voff  = (unsigned)(d * 16);      // lane's 16B (8 y) within a j-group
  unsigned pvoff = (unsigned)(d * 32);      // lane's 32B pe record within a chunk

  unsigned P0[16], P1[16], P2[16];
  uint32x4 r0, r1, pv[2], npv[2];
  float acc[32];
  unsigned carry = 0u;

  unsigned pbase = (2u * (unsigned)mt + 1u) * 32768u;  // pe chunk-0 byte offset
  int nch = 2 * mt + 2;

  #pragma unroll
  for (int m = 0; m < 32; ++m) acc[m] = 0.f;
  #pragma unroll
  for (int t = 0; t < 16; ++t){ P0[t] = 0u; P1[t] = 0u; }  // groups -2, -1 (j<0)

  // prologue: group 0 raw + pe chunk 0
  GLD4(r0, voff, xb);
  GLD4(r1, voff + 16384u, xb);
  GLD4(pv[0], pvoff + pbase, pb);
  GLD4(pv[1], pvoff + pbase + 16u, pb);
  asm volatile("s_waitcnt vmcnt(0)" ::: "memory");
  __builtin_amdgcn_sched_barrier(0);
  build_pairs(P2, r0, r1, carry);           // group 0 (y_{-1} = carry 0)

  int c = 0;
  for (;;){
    BODY(P0, P1, P2, c); if (++c == nch) break;
    BODY(P1, P2, P0, c); if (++c == nch) break;
    BODY(P2, P0, P1, c); if (++c == nch) break;
  }

  float* oc = out + ((size_t)(b * SEQ + p) * 1024 + d) + (size_t)mt * 32 * 2048;
  #pragma unroll
  for (int m = 0; m < 32; ++m)
    __builtin_nontemporal_store(acc[m], oc + (size_t)m * 2048);
}

extern "C" void kernel_launch(void* const* d_in, const int* in_sizes, int n_in,
                              void* d_out, int out_size, void* d_ws, size_t ws_size,
                              hipStream_t stream){
  const float* x       = (const float*)d_in[0];
  const float* filters = (const float*)d_in[1];
  const float* Mi      = (const float*)d_in[2];
  const float* Mf      = (const float*)d_in[3];

  char* ws = (char*)d_ws;
  unsigned short* Xb    = (unsigned short*)(ws);                              // 16 MB
  unsigned short* Y8    = (unsigned short*)(ws + (size_t)16 * 1024 * 1024);   // 16 MB
  unsigned short* MbT   = (unsigned short*)(ws + (size_t)48 * 1024 * 1024);   //  2 MB
  unsigned int*   pepk2 = (unsigned int*)  (ws + (size_t)50 * 1024 * 1024);   //  2 MB
  float* out = (float*)d_out;

  hipLaunchKernelGGL(k_cvt_x, dim3(8192), dim3(256), 0, stream, x, Xb);
  hipLaunchKernelGGL(k_tr_M,  dim3(32, 32), dim3(32, 8), 0, stream, Mi, MbT);
  hipLaunchKernelGGL(k_pe,    dim3(2, 1024), dim3(256), 0, stream, filters, Mf, pepk2);
  hipLaunchKernelGGL(k_gemm,  dim3(64, 8), dim3(256), 0, stream, Xb, MbT, Y8);
  // 65536 B dynamic LDS per block: caps residency at 2 blocks/CU (160 KiB pool)
  // -> 512 resident slots serve 1024 LPT-ordered blocks with HW backfill.
  hipLaunchKernelGGL(k_conv,  dim3(1024), dim3(256), 65536, stream, Y8, pepk2, out);
}